// Round 13
// baseline (85.755 us; speedup 1.0000x reference)
//
#include <hip/hip_runtime.h>

// ---------------------------------------------------------------------------
//  x (10,3,250,250)
//  conv1 5x5 s2 p1 + relu + pool 2x2 s1 -> p1 (10,6,123,123)
//      convpool1 (wave-pool): block 256 = 4 waves; wave = 2 pool rows x 63
//      cols; lane computes 3 vertically-adjacent conv rows (45 LDS reads ->
//      450 FMAs per ic), pool via register max + __shfl_down(1). ONE barrier,
//      no conv-output LDS.
//  conv2 3x3 s2 p1 + relu + pool -> p2 (10,15,61,61), batch stride 55816
//  fc1 (120,55815) split-K partials (float4 act loads, chunk 768)
//  fcA: fc1-reduce + fc2 relu + fc3 -> h3 (10,)
//  clsB: qnn tanh x2 (redundant per block) + RBF partials
//  clsC: final sum -> out (1,2)
//
//  MEASURED NOTES:
//   - conv weights stay in GLOBAL (uniform index -> s_load scalarization).
//     LDS-staging them: VGPR 52->168, occ 20->9.6% (round 5).
//   - cooperative whole-net fusion: 431 us (round 10) - grid.sync cost. Don't.
//   - stride-2 LDS reads are 2-way bank-aliased = free (m136).
//   - fc1 chunk 768 (R11) > 512 (R12) and > 1536 (R6): keep 768.
// ---------------------------------------------------------------------------

#define ACT_STRIDE 55816   // 55815 padded to multiple of 8

// ===== conv1 + relu + pool, wave-pool. grid (10, 16, 2), block 256 =====
// Tile: 8 pool rows (9 conv rows, 21 input rows) x 63 pool cols (64 conv
// cols, 131 input cols).
__global__ __launch_bounds__(256) void convpool1_k(
    const float* __restrict__ x, const float* __restrict__ w,
    const float* __restrict__ bias, float* __restrict__ out /*(10,6,123,123)*/) {
    const int b   = blockIdx.x;
    const int py0 = blockIdx.y * 8;
    const int px0 = blockIdx.z * 63;
    const int iy0 = 2 * py0 - 1;
    const int ix0 = 2 * px0 - 1;

    __shared__ float sx[3][21][132];  // 33.3 KB

    const int tid = threadIdx.x;

    // ---- stage 3 x 21 x 131 (coalesced, zero-padded) ----
    for (int j = tid; j < 3 * 21 * 131; j += 256) {
        int c  = j % 131;
        int r  = (j / 131) % 21;
        int ic = j / (131 * 21);
        int ix = ix0 + c, iy = iy0 + r;
        float v = 0.f;
        if ((unsigned)ix < 250u && (unsigned)iy < 250u)
            v = x[((size_t)(b * 3 + ic) * 250 + iy) * 250 + ix];
        sx[ic][r][c] = v;
    }
    __syncthreads();

    const int lane = tid & 63;         // conv col (local)
    const int wv   = tid >> 6;         // wave: pool rows py0+2wv, +1

    // ---- conv: 3 conv rows (local 2wv+j) x 1 col x 6 oc in registers ----
    float acc[3][6];
    #pragma unroll
    for (int j = 0; j < 3; ++j)
        #pragma unroll
        for (int o = 0; o < 6; ++o) acc[j][o] = bias[o];

    #pragma unroll
    for (int ic = 0; ic < 3; ++ic) {
        #pragma unroll
        for (int r = 0; r < 9; ++r) {          // thread-window input row
            float xr[5];
            #pragma unroll
            for (int c = 0; c < 5; ++c)
                xr[c] = sx[ic][4 * wv + r][2 * lane + c];
            #pragma unroll
            for (int j = 0; j < 3; ++j) {      // conv row j uses ky = r-2j
                int ky = r - 2 * j;
                if (ky >= 0 && ky < 5) {
                    #pragma unroll
                    for (int c = 0; c < 5; ++c) {
                        #pragma unroll
                        for (int o = 0; o < 6; ++o)
                            acc[j][o] = fmaf(w[((o * 3 + ic) * 5 + ky) * 5 + c],
                                             xr[c], acc[j][o]);
                    }
                }
            }
        }
    }

    // ---- pool: vertical in-reg, horizontal via shfl; relu; store ----
    #pragma unroll
    for (int j = 0; j < 2; ++j) {
        const int py = py0 + 2 * wv + j;
        const int px = px0 + lane;
        #pragma unroll
        for (int o = 0; o < 6; ++o) {
            float m  = fmaxf(acc[j][o], acc[j + 1][o]);
            float nb = __shfl_down(m, 1);      // all lanes execute
            if (lane < 63 && py < 123 && px < 123)
                out[((size_t)(b * 6 + o) * 123 + py) * 123 + px] =
                    fmaxf(fmaxf(m, nb), 0.f);
        }
    }
}

// ===== conv2 + relu + pool fused. grid (10, 31, 2), block 128 =====
__global__ __launch_bounds__(128) void convpool2_k(
    const float* __restrict__ in /*(10,6,123,123)*/, const float* __restrict__ w,
    const float* __restrict__ bias, float* __restrict__ out /*padded (10,55816)*/) {
    const int b   = blockIdx.x;
    const int py0 = blockIdx.y * 2;
    const int px0 = blockIdx.z * 31;
    const int n_py = (61 - py0) < 2 ? (61 - py0) : 2;
    const int n_oy = n_py + 1;
    const int iy0 = 2 * py0 - 1;
    const int ix0 = 2 * px0 - 1;

    __shared__ float sx[6][7][68];
    __shared__ float so[15][3][32];

    const int tid = threadIdx.x;

    for (int j = tid; j < 6 * 7 * 65; j += 128) {
        int col = j % 65;
        int r   = (j / 65) % 7;
        int ic  = j / (65 * 7);
        int ix = ix0 + col, iy = iy0 + r;
        float v = 0.f;
        if ((unsigned)ix < 123u && (unsigned)iy < 123u)
            v = in[((size_t)(b * 6 + ic) * 123 + iy) * 123 + ix];
        sx[ic][r][col] = v;
    }
    __syncthreads();

    for (int p = tid; p < n_oy * 32; p += 128) {
        int oxl = p & 31;
        int oyl = p >> 5;
        if (px0 + oxl < 62) {
            float acc[15];
            #pragma unroll
            for (int o = 0; o < 15; ++o) acc[o] = bias[o];
            #pragma unroll
            for (int ic = 0; ic < 6; ++ic) {
                #pragma unroll
                for (int ky = 0; ky < 3; ++ky) {
                    const float* xr = &sx[ic][2 * oyl + ky][2 * oxl];
                    #pragma unroll
                    for (int kx = 0; kx < 3; ++kx) {
                        float xv = xr[kx];
                        #pragma unroll
                        for (int o = 0; o < 15; ++o)
                            acc[o] += w[((o * 6 + ic) * 3 + ky) * 3 + kx] * xv;
                    }
                }
            }
            #pragma unroll
            for (int o = 0; o < 15; ++o) so[o][oyl][oxl] = fmaxf(acc[o], 0.f);
        }
    }
    __syncthreads();

    for (int j = tid; j < 15 * 2 * 31; j += 128) {
        int pxl = j % 31;
        int pyl = (j / 31) & 1;
        int oc  = j / 62;
        int px = px0 + pxl, py = py0 + pyl;
        if (pyl < n_py && px < 61) {
            float v = fmaxf(fmaxf(so[oc][pyl][pxl],     so[oc][pyl][pxl + 1]),
                            fmaxf(so[oc][pyl + 1][pxl], so[oc][pyl + 1][pxl + 1]));
            out[(size_t)b * ACT_STRIDE + ((size_t)oc * 61 + py) * 61 + px] = v;
        }
    }
}

// ================= fc1: split-K partials =================
#define FC1_K      55815
#define FC1_CHUNK  768
#define FC1_NC     73
#define FC1_RT     15

// grid (15, 73), block 256. Wave w owns rows rt*8 + {2w, 2w+1}.
__global__ __launch_bounds__(256) void fc1_partial_k(
    const float* __restrict__ act /*(10, ACT_STRIDE)*/,
    const float* __restrict__ w   /*(120, 55815)*/,
    float* __restrict__ partials  /*(73,120,10)*/) {
    int rt  = blockIdx.x;
    int c   = blockIdx.y;
    int tid = threadIdx.x;
    int wave = tid >> 6, lane = tid & 63;
    int k0 = c * FC1_CHUNK;
    int k1 = k0 + FC1_CHUNK; if (k1 > FC1_K) k1 = FC1_K;
    int r0 = rt * 8 + wave * 2;
    const float* w0 = w + (size_t)r0 * FC1_K;
    const float* w1 = w + (size_t)(r0 + 1) * FC1_K;

    float acc0[10], acc1[10];
    #pragma unroll
    for (int b = 0; b < 10; ++b) { acc0[b] = 0.f; acc1[b] = 0.f; }

    for (int k = k0 + lane * 4; k < k1; k += 256) {
        if (k + 4 <= k1) {
            float4 a4[10];
            #pragma unroll
            for (int b = 0; b < 10; ++b)
                a4[b] = *reinterpret_cast<const float4*>(act + (size_t)b * ACT_STRIDE + k);
            float w00 = w0[k], w01 = w0[k + 1], w02 = w0[k + 2], w03 = w0[k + 3];
            float w10 = w1[k], w11 = w1[k + 1], w12 = w1[k + 2], w13 = w1[k + 3];
            #pragma unroll
            for (int b = 0; b < 10; ++b) {
                acc0[b] += w00 * a4[b].x + w01 * a4[b].y + w02 * a4[b].z + w03 * a4[b].w;
                acc1[b] += w10 * a4[b].x + w11 * a4[b].y + w12 * a4[b].z + w13 * a4[b].w;
            }
        } else {
            for (int j = 0; j < k1 - k; ++j) {
                float wv0 = w0[k + j], wv1 = w1[k + j];
                #pragma unroll
                for (int b = 0; b < 10; ++b) {
                    float av = act[(size_t)b * ACT_STRIDE + k + j];
                    acc0[b] += wv0 * av;
                    acc1[b] += wv1 * av;
                }
            }
        }
    }
    #pragma unroll
    for (int b = 0; b < 10; ++b) {
        float v0 = acc0[b], v1 = acc1[b];
        for (int off = 32; off > 0; off >>= 1) {
            v0 += __shfl_down(v0, off);
            v1 += __shfl_down(v1, off);
        }
        if (lane == 0) {
            size_t base = ((size_t)c * 120 + r0) * 10;
            partials[base + b]      = v0;
            partials[base + 10 + b] = v1;
        }
    }
}

// ===== fcA: fc1-reduce + fc2 + fc3. grid 10 (one block per batch) x 128 =====
__global__ __launch_bounds__(128) void fcA_k(
    const float* __restrict__ part /*(73,120,10)*/, const float* __restrict__ fc1_b,
    const float* __restrict__ fc2_w, const float* __restrict__ fc2_b,
    const float* __restrict__ fc3_w, const float* __restrict__ fc3_b,
    float* __restrict__ h3 /*(10,)*/) {
    const int b = blockIdx.x;
    const int tid = threadIdx.x;
    __shared__ float s_act[120];
    __shared__ float s_fc2[84];

    if (tid < 120) {
        float s = 0.f;
        for (int c = 0; c < FC1_NC; ++c) s += part[((size_t)c * 120 + tid) * 10 + b];
        s_act[tid] = fmaxf(s + fc1_b[tid], 0.f);
    }
    __syncthreads();
    if (tid < 84) {
        float acc = fc2_b[tid];
        #pragma unroll 4
        for (int k = 0; k < 120; ++k) acc += s_act[k] * fc2_w[tid * 120 + k];
        s_fc2[tid] = fmaxf(acc, 0.f);
    }
    __syncthreads();
    if (tid < 64) {
        float v = s_fc2[tid] * fc3_w[tid];
        if (tid < 20) v += s_fc2[tid + 64] * fc3_w[tid + 64];
        for (int off = 32; off > 0; off >>= 1) v += __shfl_down(v, off);
        if (tid == 0) h3[b] = v + fc3_b[0];
    }
}

// ===== clsB: qnn (redundant per block) + RBF partials. 64 blocks x 128 =====
__global__ __launch_bounds__(128) void clsB_k(
    const float* __restrict__ h3 /*(10,)*/,
    const float* __restrict__ qw1, const float* __restrict__ qw2,
    const float* __restrict__ ts /*(8192,5)*/, const float* __restrict__ kw /*(2,8192)*/,
    float* __restrict__ partials /*(64,2)*/) {
    int tid = threadIdx.x;
    __shared__ float s_h3[10], s_s1[20], s_fs[5];
    if (tid < 10) s_h3[tid] = h3[tid];
    __syncthreads();
    if (tid < 20) {
        float acc = 0.f;
        for (int b = 0; b < 10; ++b) acc += qw1[tid * 10 + b] * s_h3[b];
        s_s1[tid] = tanhf(acc);
    }
    __syncthreads();
    if (tid < 5) {
        float acc = 0.f;
        for (int j = 0; j < 20; ++j) acc += qw2[tid * 20 + j] * s_s1[j];
        s_fs[tid] = tanhf(acc);
    }
    __syncthreads();

    float f0 = s_fs[0], f1 = s_fs[1], f2 = s_fs[2], f3 = s_fs[3], f4 = s_fs[4];
    int n = blockIdx.x * 128 + tid;
    const float* t = ts + (size_t)n * 5;
    float d0 = f0 - t[0], d1 = f1 - t[1], d2 = f2 - t[2], d3 = f3 - t[3], d4 = f4 - t[4];
    float Kv = expf(-(d0 * d0 + d1 * d1 + d2 * d2 + d3 * d3 + d4 * d4));
    float a0 = Kv * kw[n];
    float a1 = Kv * kw[8192 + n];
    for (int off = 32; off > 0; off >>= 1) {
        a0 += __shfl_down(a0, off);
        a1 += __shfl_down(a1, off);
    }
    __shared__ float l0[2], l1[2];
    int wave = tid >> 6, lane = tid & 63;
    if (lane == 0) { l0[wave] = a0; l1[wave] = a1; }
    __syncthreads();
    if (tid == 0) {
        partials[blockIdx.x * 2 + 0] = l0[0] + l0[1];
        partials[blockIdx.x * 2 + 1] = l1[0] + l1[1];
    }
}

__global__ void clsC_k(const float* __restrict__ partials,
                       const float* __restrict__ kb, float* __restrict__ out) {
    int c = threadIdx.x;
    if (c < 2) {
        float acc = kb[c];
        for (int i = 0; i < 64; ++i) acc += partials[i * 2 + c];
        out[c] = acc;
    }
}

extern "C" void kernel_launch(void* const* d_in, const int* in_sizes, int n_in,
                              void* d_out, int out_size, void* d_ws, size_t ws_size,
                              hipStream_t stream) {
    const float* x        = (const float*)d_in[0];
    const float* conv1_w  = (const float*)d_in[1];
    const float* conv1_b  = (const float*)d_in[2];
    const float* conv2_w  = (const float*)d_in[3];
    const float* conv2_b  = (const float*)d_in[4];
    const float* fc1_w    = (const float*)d_in[5];
    const float* fc1_b    = (const float*)d_in[6];
    const float* fc2_w    = (const float*)d_in[7];
    const float* fc2_b    = (const float*)d_in[8];
    const float* fc3_w    = (const float*)d_in[9];
    const float* fc3_b    = (const float*)d_in[10];
    const float* qnn_w1   = (const float*)d_in[11];
    const float* qnn_w2   = (const float*)d_in[12];
    const float* tstates  = (const float*)d_in[13];
    const float* kcls_w   = (const float*)d_in[14];
    const float* kcls_b   = (const float*)d_in[15];

    float* ws = (float*)d_ws;
    float* p1       = ws;                  // 10*6*123*123 = 907740
    float* p2       = p1 + 907740;         // 10*ACT_STRIDE = 558160 (16B-aligned)
    float* fc1_part = p2 + 558160;         // 73*120*10 = 87600
    float* h3       = fc1_part + 87600;    // 16
    float* partials = h3 + 16;             // 128

    convpool1_k<<<dim3(10, 16, 2), 256, 0, stream>>>(x, conv1_w, conv1_b, p1);
    convpool2_k<<<dim3(10, 31, 2), 128, 0, stream>>>(p1, conv2_w, conv2_b, p2);
    fc1_partial_k<<<dim3(FC1_RT, FC1_NC), 256, 0, stream>>>(p2, fc1_w, fc1_part);
    fcA_k<<<10, 128, 0, stream>>>(fc1_part, fc1_b, fc2_w, fc2_b, fc3_w, fc3_b, h3);
    clsB_k<<<64, 128, 0, stream>>>(h3, qnn_w1, qnn_w2, tstates, kcls_w, partials);
    clsC_k<<<1, 64, 0, stream>>>(partials, kcls_b, (float*)d_out);
}

// Round 14
// 78.148 us; speedup vs baseline: 1.0973x; 1.0973x over previous
//
#include <hip/hip_runtime.h>

// ---------------------------------------------------------------------------
//  x (10,3,250,250)
//  conv1 5x5 s2 p1 + relu + pool 2x2 s1 -> p1 (10,6,123,123)
//      convpool1: 4 pool rows x 31 pool cols per block, 256 threads,
//      grid (10,31,4) = 1240 blocks, LDS 14.4 KB -> ~4.8 blocks/CU.
//  conv2 3x3 s2 p1 + relu + pool -> p2 (10,15,61,61), batch stride 55816
//  fc1 (120,55815) split-K partials (float4 act loads, chunk 768)
//  fcA: fc1-reduce + fc2 relu + fc3 -> h3 (10,)
//  clsB: qnn tanh x2 (redundant per block) + RBF partials
//  clsC: final sum -> out (1,2)
//
//  MEASURED NOTES:
//   - conv weights stay in GLOBAL (uniform index -> s_load scalarization).
//     LDS-staging them: VGPR 52->168, occ 20->9.6% (round 5).
//   - cooperative whole-net fusion: 431 us (round 10). Don't.
//   - stride-2 LDS reads are 2-way bank-aliased = free (m136).
//   - fc1 chunk 768 best (R11 80.9 vs R12 512-chunk 84.1, R6 1536 ~86).
//   - conv1 instruction-level variants (deinterleave, reg-pool, wave-pool,
//     win-batch) all within noise or worse at ~600 blocks: not VALU-bound.
//     This round tests block-parallelism (620->1240) as the single variable.
// ---------------------------------------------------------------------------

#define ACT_STRIDE 55816   // 55815 padded to multiple of 8

// ===== conv1 + relu + pool fused. grid (10, 31, 4), block 256 =====
// Tile: 4 pool rows (5 conv rows, 13 input rows) x 31 pool cols (32 conv
// cols, 67 input cols).
__global__ __launch_bounds__(256) void convpool1_k(
    const float* __restrict__ x, const float* __restrict__ w,
    const float* __restrict__ bias, float* __restrict__ out /*(10,6,123,123)*/) {
    const int b   = blockIdx.x;
    const int py0 = blockIdx.y * 4;
    const int px0 = blockIdx.z * 31;
    const int n_py = (123 - py0) < 4 ? (123 - py0) : 4;
    const int n_oy = n_py + 1;
    const int iy0 = 2 * py0 - 1;
    const int ix0 = 2 * px0 - 1;

    __shared__ float sx[3][13][68];   // input tile (13 rows x 67 cols used)
    __shared__ float so[6][5][32];    // conv outputs

    const int tid = threadIdx.x;

    // ---- stage 3 x 13 x 67 (coalesced, zero-padded) ----
    for (int j = tid; j < 3 * 13 * 67; j += 256) {
        int c  = j % 67;
        int r  = (j / 67) % 13;
        int ic = j / (67 * 13);
        int ix = ix0 + c, iy = iy0 + r;
        float v = 0.f;
        if ((unsigned)ix < 250u && (unsigned)iy < 250u)
            v = x[((size_t)(b * 3 + ic) * 250 + iy) * 250 + ix];
        sx[ic][r][c] = v;
    }
    __syncthreads();

    // ---- conv: each thread one (oyl, oxl) for all 6 oc ----
    for (int p = tid; p < n_oy * 32; p += 256) {
        int oxl = p & 31;
        int oyl = p >> 5;
        if (px0 + oxl < 124) {
            float acc[6];
            #pragma unroll
            for (int o = 0; o < 6; ++o) acc[o] = bias[o];
            #pragma unroll
            for (int ic = 0; ic < 3; ++ic) {
                #pragma unroll
                for (int ky = 0; ky < 5; ++ky) {
                    const float* xr = &sx[ic][2 * oyl + ky][2 * oxl];
                    #pragma unroll
                    for (int kx = 0; kx < 5; ++kx) {
                        float xv = xr[kx];
                        #pragma unroll
                        for (int o = 0; o < 6; ++o)
                            acc[o] += w[((o * 3 + ic) * 5 + ky) * 5 + kx] * xv;
                    }
                }
            }
            #pragma unroll
            for (int o = 0; o < 6; ++o) so[o][oyl][oxl] = fmaxf(acc[o], 0.f);
        }
    }
    __syncthreads();

    // ---- pool 2x2 s1 + store: 6 oc x 4 py x 31 px jobs ----
    for (int j = tid; j < 6 * 4 * 31; j += 256) {
        int pxl = j % 31;
        int pyl = (j / 31) & 3;
        int oc  = j / 124;
        int px = px0 + pxl, py = py0 + pyl;
        if (pyl < n_py && px < 123) {
            float v = fmaxf(fmaxf(so[oc][pyl][pxl],     so[oc][pyl][pxl + 1]),
                            fmaxf(so[oc][pyl + 1][pxl], so[oc][pyl + 1][pxl + 1]));
            out[((size_t)(b * 6 + oc) * 123 + py) * 123 + px] = v;
        }
    }
}

// ===== conv2 + relu + pool fused. grid (10, 31, 2), block 128 =====
__global__ __launch_bounds__(128) void convpool2_k(
    const float* __restrict__ in /*(10,6,123,123)*/, const float* __restrict__ w,
    const float* __restrict__ bias, float* __restrict__ out /*padded (10,55816)*/) {
    const int b   = blockIdx.x;
    const int py0 = blockIdx.y * 2;
    const int px0 = blockIdx.z * 31;
    const int n_py = (61 - py0) < 2 ? (61 - py0) : 2;
    const int n_oy = n_py + 1;
    const int iy0 = 2 * py0 - 1;
    const int ix0 = 2 * px0 - 1;

    __shared__ float sx[6][7][68];
    __shared__ float so[15][3][32];

    const int tid = threadIdx.x;

    for (int j = tid; j < 6 * 7 * 65; j += 128) {
        int col = j % 65;
        int r   = (j / 65) % 7;
        int ic  = j / (65 * 7);
        int ix = ix0 + col, iy = iy0 + r;
        float v = 0.f;
        if ((unsigned)ix < 123u && (unsigned)iy < 123u)
            v = in[((size_t)(b * 6 + ic) * 123 + iy) * 123 + ix];
        sx[ic][r][col] = v;
    }
    __syncthreads();

    for (int p = tid; p < n_oy * 32; p += 128) {
        int oxl = p & 31;
        int oyl = p >> 5;
        if (px0 + oxl < 62) {
            float acc[15];
            #pragma unroll
            for (int o = 0; o < 15; ++o) acc[o] = bias[o];
            #pragma unroll
            for (int ic = 0; ic < 6; ++ic) {
                #pragma unroll
                for (int ky = 0; ky < 3; ++ky) {
                    const float* xr = &sx[ic][2 * oyl + ky][2 * oxl];
                    #pragma unroll
                    for (int kx = 0; kx < 3; ++kx) {
                        float xv = xr[kx];
                        #pragma unroll
                        for (int o = 0; o < 15; ++o)
                            acc[o] += w[((o * 6 + ic) * 3 + ky) * 3 + kx] * xv;
                    }
                }
            }
            #pragma unroll
            for (int o = 0; o < 15; ++o) so[o][oyl][oxl] = fmaxf(acc[o], 0.f);
        }
    }
    __syncthreads();

    for (int j = tid; j < 15 * 2 * 31; j += 128) {
        int pxl = j % 31;
        int pyl = (j / 31) & 1;
        int oc  = j / 62;
        int px = px0 + pxl, py = py0 + pyl;
        if (pyl < n_py && px < 61) {
            float v = fmaxf(fmaxf(so[oc][pyl][pxl],     so[oc][pyl][pxl + 1]),
                            fmaxf(so[oc][pyl + 1][pxl], so[oc][pyl + 1][pxl + 1]));
            out[(size_t)b * ACT_STRIDE + ((size_t)oc * 61 + py) * 61 + px] = v;
        }
    }
}

// ================= fc1: split-K partials =================
#define FC1_K      55815
#define FC1_CHUNK  768
#define FC1_NC     73
#define FC1_RT     15

// grid (15, 73), block 256. Wave w owns rows rt*8 + {2w, 2w+1}.
__global__ __launch_bounds__(256) void fc1_partial_k(
    const float* __restrict__ act /*(10, ACT_STRIDE)*/,
    const float* __restrict__ w   /*(120, 55815)*/,
    float* __restrict__ partials  /*(73,120,10)*/) {
    int rt  = blockIdx.x;
    int c   = blockIdx.y;
    int tid = threadIdx.x;
    int wave = tid >> 6, lane = tid & 63;
    int k0 = c * FC1_CHUNK;
    int k1 = k0 + FC1_CHUNK; if (k1 > FC1_K) k1 = FC1_K;
    int r0 = rt * 8 + wave * 2;
    const float* w0 = w + (size_t)r0 * FC1_K;
    const float* w1 = w + (size_t)(r0 + 1) * FC1_K;

    float acc0[10], acc1[10];
    #pragma unroll
    for (int b = 0; b < 10; ++b) { acc0[b] = 0.f; acc1[b] = 0.f; }

    for (int k = k0 + lane * 4; k < k1; k += 256) {
        if (k + 4 <= k1) {
            float4 a4[10];
            #pragma unroll
            for (int b = 0; b < 10; ++b)
                a4[b] = *reinterpret_cast<const float4*>(act + (size_t)b * ACT_STRIDE + k);
            float w00 = w0[k], w01 = w0[k + 1], w02 = w0[k + 2], w03 = w0[k + 3];
            float w10 = w1[k], w11 = w1[k + 1], w12 = w1[k + 2], w13 = w1[k + 3];
            #pragma unroll
            for (int b = 0; b < 10; ++b) {
                acc0[b] += w00 * a4[b].x + w01 * a4[b].y + w02 * a4[b].z + w03 * a4[b].w;
                acc1[b] += w10 * a4[b].x + w11 * a4[b].y + w12 * a4[b].z + w13 * a4[b].w;
            }
        } else {
            for (int j = 0; j < k1 - k; ++j) {
                float wv0 = w0[k + j], wv1 = w1[k + j];
                #pragma unroll
                for (int b = 0; b < 10; ++b) {
                    float av = act[(size_t)b * ACT_STRIDE + k + j];
                    acc0[b] += wv0 * av;
                    acc1[b] += wv1 * av;
                }
            }
        }
    }
    #pragma unroll
    for (int b = 0; b < 10; ++b) {
        float v0 = acc0[b], v1 = acc1[b];
        for (int off = 32; off > 0; off >>= 1) {
            v0 += __shfl_down(v0, off);
            v1 += __shfl_down(v1, off);
        }
        if (lane == 0) {
            size_t base = ((size_t)c * 120 + r0) * 10;
            partials[base + b]      = v0;
            partials[base + 10 + b] = v1;
        }
    }
}

// ===== fcA: fc1-reduce + fc2 + fc3. grid 10 (one block per batch) x 128 =====
__global__ __launch_bounds__(128) void fcA_k(
    const float* __restrict__ part /*(73,120,10)*/, const float* __restrict__ fc1_b,
    const float* __restrict__ fc2_w, const float* __restrict__ fc2_b,
    const float* __restrict__ fc3_w, const float* __restrict__ fc3_b,
    float* __restrict__ h3 /*(10,)*/) {
    const int b = blockIdx.x;
    const int tid = threadIdx.x;
    __shared__ float s_act[120];
    __shared__ float s_fc2[84];

    if (tid < 120) {
        float s = 0.f;
        for (int c = 0; c < FC1_NC; ++c) s += part[((size_t)c * 120 + tid) * 10 + b];
        s_act[tid] = fmaxf(s + fc1_b[tid], 0.f);
    }
    __syncthreads();
    if (tid < 84) {
        float acc = fc2_b[tid];
        #pragma unroll 4
        for (int k = 0; k < 120; ++k) acc += s_act[k] * fc2_w[tid * 120 + k];
        s_fc2[tid] = fmaxf(acc, 0.f);
    }
    __syncthreads();
    if (tid < 64) {
        float v = s_fc2[tid] * fc3_w[tid];
        if (tid < 20) v += s_fc2[tid + 64] * fc3_w[tid + 64];
        for (int off = 32; off > 0; off >>= 1) v += __shfl_down(v, off);
        if (tid == 0) h3[b] = v + fc3_b[0];
    }
}

// ===== clsB: qnn (redundant per block) + RBF partials. 64 blocks x 128 =====
__global__ __launch_bounds__(128) void clsB_k(
    const float* __restrict__ h3 /*(10,)*/,
    const float* __restrict__ qw1, const float* __restrict__ qw2,
    const float* __restrict__ ts /*(8192,5)*/, const float* __restrict__ kw /*(2,8192)*/,
    float* __restrict__ partials /*(64,2)*/) {
    int tid = threadIdx.x;
    __shared__ float s_h3[10], s_s1[20], s_fs[5];
    if (tid < 10) s_h3[tid] = h3[tid];
    __syncthreads();
    if (tid < 20) {
        float acc = 0.f;
        for (int b = 0; b < 10; ++b) acc += qw1[tid * 10 + b] * s_h3[b];
        s_s1[tid] = tanhf(acc);
    }
    __syncthreads();
    if (tid < 5) {
        float acc = 0.f;
        for (int j = 0; j < 20; ++j) acc += qw2[tid * 20 + j] * s_s1[j];
        s_fs[tid] = tanhf(acc);
    }
    __syncthreads();

    float f0 = s_fs[0], f1 = s_fs[1], f2 = s_fs[2], f3 = s_fs[3], f4 = s_fs[4];
    int n = blockIdx.x * 128 + tid;
    const float* t = ts + (size_t)n * 5;
    float d0 = f0 - t[0], d1 = f1 - t[1], d2 = f2 - t[2], d3 = f3 - t[3], d4 = f4 - t[4];
    float Kv = expf(-(d0 * d0 + d1 * d1 + d2 * d2 + d3 * d3 + d4 * d4));
    float a0 = Kv * kw[n];
    float a1 = Kv * kw[8192 + n];
    for (int off = 32; off > 0; off >>= 1) {
        a0 += __shfl_down(a0, off);
        a1 += __shfl_down(a1, off);
    }
    __shared__ float l0[2], l1[2];
    int wave = tid >> 6, lane = tid & 63;
    if (lane == 0) { l0[wave] = a0; l1[wave] = a1; }
    __syncthreads();
    if (tid == 0) {
        partials[blockIdx.x * 2 + 0] = l0[0] + l0[1];
        partials[blockIdx.x * 2 + 1] = l1[0] + l1[1];
    }
}

__global__ void clsC_k(const float* __restrict__ partials,
                       const float* __restrict__ kb, float* __restrict__ out) {
    int c = threadIdx.x;
    if (c < 2) {
        float acc = kb[c];
        for (int i = 0; i < 64; ++i) acc += partials[i * 2 + c];
        out[c] = acc;
    }
}

extern "C" void kernel_launch(void* const* d_in, const int* in_sizes, int n_in,
                              void* d_out, int out_size, void* d_ws, size_t ws_size,
                              hipStream_t stream) {
    const float* x        = (const float*)d_in[0];
    const float* conv1_w  = (const float*)d_in[1];
    const float* conv1_b  = (const float*)d_in[2];
    const float* conv2_w  = (const float*)d_in[3];
    const float* conv2_b  = (const float*)d_in[4];
    const float* fc1_w    = (const float*)d_in[5];
    const float* fc1_b    = (const float*)d_in[6];
    const float* fc2_w    = (const float*)d_in[7];
    const float* fc2_b    = (const float*)d_in[8];
    const float* fc3_w    = (const float*)d_in[9];
    const float* fc3_b    = (const float*)d_in[10];
    const float* qnn_w1   = (const float*)d_in[11];
    const float* qnn_w2   = (const float*)d_in[12];
    const float* tstates  = (const float*)d_in[13];
    const float* kcls_w   = (const float*)d_in[14];
    const float* kcls_b   = (const float*)d_in[15];

    float* ws = (float*)d_ws;
    float* p1       = ws;                  // 10*6*123*123 = 907740
    float* p2       = p1 + 907740;         // 10*ACT_STRIDE = 558160 (16B-aligned)
    float* fc1_part = p2 + 558160;         // 73*120*10 = 87600
    float* h3       = fc1_part + 87600;    // 16
    float* partials = h3 + 16;             // 128

    convpool1_k<<<dim3(10, 31, 4), 256, 0, stream>>>(x, conv1_w, conv1_b, p1);
    convpool2_k<<<dim3(10, 31, 2), 128, 0, stream>>>(p1, conv2_w, conv2_b, p2);
    fc1_partial_k<<<dim3(FC1_RT, FC1_NC), 256, 0, stream>>>(p2, fc1_w, fc1_part);
    fcA_k<<<10, 128, 0, stream>>>(fc1_part, fc1_b, fc2_w, fc2_b, fc3_w, fc3_b, h3);
    clsB_k<<<64, 128, 0, stream>>>(h3, qnn_w1, qnn_w2, tstates, kcls_w, partials);
    clsC_k<<<1, 64, 0, stream>>>(partials, kcls_b, (float*)d_out);
}

// Round 15
// 75.145 us; speedup vs baseline: 1.1412x; 1.0400x over previous
//
#include <hip/hip_runtime.h>

// ---------------------------------------------------------------------------
//  x (10,3,250,250)
//  conv1 5x5 s2 p1 + relu + pool 2x2 s1 -> p1 (10,6,123,123)
//      convpool1: 4 pool rows x 31 pool cols per block, 256 threads,
//      grid (10,31,4) = 1240 blocks, LDS 14.4 KB -> ~4.8 blocks/CU.
//  conv2 3x3 s2 p1 + relu + pool -> p2 (10,15,61,61), batch stride 55816
//      convpool2: 2 pool rows x 16 pool cols per block, 128 threads,
//      grid (10,31,4) = 1240 blocks, LDS ~10 KB (block-parallelism lever).
//  fc1 (120,55815) split-K partials (float4 act loads, chunk 768)
//  fcA: fc1-reduce + fc2 relu + fc3 -> h3 (10,)
//  clsB: qnn tanh x2 (redundant per block) + RBF partials
//  clsC: final sum -> out (1,2)
//
//  MEASURED NOTES:
//   - conv weights stay in GLOBAL (uniform index -> s_load scalarization).
//     LDS-staging them: VGPR 52->168, occ 20->9.6% (round 5).
//   - cooperative whole-net fusion: 431 us (round 10). Don't.
//   - stride-2 LDS reads are 2-way bank-aliased = free (m136).
//   - fc1 chunk 768 best (R11 80.9 vs R12 512-chunk 84.1, R6 1536 ~86).
//   - conv1 instruction-level variants (deinterleave, reg-pool, wave-pool,
//     win-batch) all within noise at ~600 blocks: latency-, not VALU-bound.
//   - BLOCK-PARALLELISM is the proven lever: conv1 620->1240 blocks gave
//     80.9->78.1 us (R14). This round applies it to conv2.
// ---------------------------------------------------------------------------

#define ACT_STRIDE 55816   // 55815 padded to multiple of 8

// ===== conv1 + relu + pool fused. grid (10, 31, 4), block 256 =====
// Tile: 4 pool rows (5 conv rows, 13 input rows) x 31 pool cols (32 conv
// cols, 67 input cols).
__global__ __launch_bounds__(256) void convpool1_k(
    const float* __restrict__ x, const float* __restrict__ w,
    const float* __restrict__ bias, float* __restrict__ out /*(10,6,123,123)*/) {
    const int b   = blockIdx.x;
    const int py0 = blockIdx.y * 4;
    const int px0 = blockIdx.z * 31;
    const int n_py = (123 - py0) < 4 ? (123 - py0) : 4;
    const int n_oy = n_py + 1;
    const int iy0 = 2 * py0 - 1;
    const int ix0 = 2 * px0 - 1;

    __shared__ float sx[3][13][68];   // input tile (13 rows x 67 cols used)
    __shared__ float so[6][5][32];    // conv outputs

    const int tid = threadIdx.x;

    // ---- stage 3 x 13 x 67 (coalesced, zero-padded) ----
    for (int j = tid; j < 3 * 13 * 67; j += 256) {
        int c  = j % 67;
        int r  = (j / 67) % 13;
        int ic = j / (67 * 13);
        int ix = ix0 + c, iy = iy0 + r;
        float v = 0.f;
        if ((unsigned)ix < 250u && (unsigned)iy < 250u)
            v = x[((size_t)(b * 3 + ic) * 250 + iy) * 250 + ix];
        sx[ic][r][c] = v;
    }
    __syncthreads();

    // ---- conv: each thread one (oyl, oxl) for all 6 oc ----
    for (int p = tid; p < n_oy * 32; p += 256) {
        int oxl = p & 31;
        int oyl = p >> 5;
        if (px0 + oxl < 124) {
            float acc[6];
            #pragma unroll
            for (int o = 0; o < 6; ++o) acc[o] = bias[o];
            #pragma unroll
            for (int ic = 0; ic < 3; ++ic) {
                #pragma unroll
                for (int ky = 0; ky < 5; ++ky) {
                    const float* xr = &sx[ic][2 * oyl + ky][2 * oxl];
                    #pragma unroll
                    for (int kx = 0; kx < 5; ++kx) {
                        float xv = xr[kx];
                        #pragma unroll
                        for (int o = 0; o < 6; ++o)
                            acc[o] += w[((o * 3 + ic) * 5 + ky) * 5 + kx] * xv;
                    }
                }
            }
            #pragma unroll
            for (int o = 0; o < 6; ++o) so[o][oyl][oxl] = fmaxf(acc[o], 0.f);
        }
    }
    __syncthreads();

    // ---- pool 2x2 s1 + store: 6 oc x 4 py x 31 px jobs ----
    for (int j = tid; j < 6 * 4 * 31; j += 256) {
        int pxl = j % 31;
        int pyl = (j / 31) & 3;
        int oc  = j / 124;
        int px = px0 + pxl, py = py0 + pyl;
        if (pyl < n_py && px < 123) {
            float v = fmaxf(fmaxf(so[oc][pyl][pxl],     so[oc][pyl][pxl + 1]),
                            fmaxf(so[oc][pyl + 1][pxl], so[oc][pyl + 1][pxl + 1]));
            out[((size_t)(b * 6 + oc) * 123 + py) * 123 + px] = v;
        }
    }
}

// ===== conv2 + relu + pool fused. grid (10, 31, 4), block 128 =====
// Tile: 2 pool rows (3 conv rows, 7 input rows) x 16 pool cols (17 conv
// cols, 35 input cols). ~10 KB LDS -> high block residency.
__global__ __launch_bounds__(128) void convpool2_k(
    const float* __restrict__ in /*(10,6,123,123)*/, const float* __restrict__ w,
    const float* __restrict__ bias, float* __restrict__ out /*padded (10,55816)*/) {
    const int b   = blockIdx.x;
    const int py0 = blockIdx.y * 2;
    const int px0 = blockIdx.z * 16;
    const int n_py = (61 - py0) < 2 ? (61 - py0) : 2;
    const int n_oy = n_py + 1;
    const int iy0 = 2 * py0 - 1;
    const int ix0 = 2 * px0 - 1;

    __shared__ float sx[6][7][36];    // 6 ic x 7 rows x 35 cols used
    __shared__ float so[15][3][20];   // 15 oc x 3 conv rows x 17 cols used

    const int tid = threadIdx.x;

    for (int j = tid; j < 6 * 7 * 35; j += 128) {
        int col = j % 35;
        int r   = (j / 35) % 7;
        int ic  = j / (35 * 7);
        int ix = ix0 + col, iy = iy0 + r;
        float v = 0.f;
        if ((unsigned)ix < 123u && (unsigned)iy < 123u)
            v = in[((size_t)(b * 6 + ic) * 123 + iy) * 123 + ix];
        sx[ic][r][col] = v;
    }
    __syncthreads();

    // conv positions: n_oy x 17 (<=51) -> one pass, all 15 oc per thread
    for (int p = tid; p < n_oy * 17; p += 128) {
        int oxl = p % 17;
        int oyl = p / 17;
        if (px0 + oxl < 62) {
            float acc[15];
            #pragma unroll
            for (int o = 0; o < 15; ++o) acc[o] = bias[o];
            #pragma unroll
            for (int ic = 0; ic < 6; ++ic) {
                #pragma unroll
                for (int ky = 0; ky < 3; ++ky) {
                    const float* xr = &sx[ic][2 * oyl + ky][2 * oxl];
                    #pragma unroll
                    for (int kx = 0; kx < 3; ++kx) {
                        float xv = xr[kx];
                        #pragma unroll
                        for (int o = 0; o < 15; ++o)
                            acc[o] += w[((o * 6 + ic) * 3 + ky) * 3 + kx] * xv;
                    }
                }
            }
            #pragma unroll
            for (int o = 0; o < 15; ++o) so[o][oyl][oxl] = fmaxf(acc[o], 0.f);
        }
    }
    __syncthreads();

    // pool: 15 oc x 2 py x 16 px = 480 jobs
    for (int j = tid; j < 15 * 2 * 16; j += 128) {
        int pxl = j & 15;
        int pyl = (j >> 4) & 1;
        int oc  = j >> 5;
        int px = px0 + pxl, py = py0 + pyl;
        if (pyl < n_py && px < 61) {
            float v = fmaxf(fmaxf(so[oc][pyl][pxl],     so[oc][pyl][pxl + 1]),
                            fmaxf(so[oc][pyl + 1][pxl], so[oc][pyl + 1][pxl + 1]));
            out[(size_t)b * ACT_STRIDE + ((size_t)oc * 61 + py) * 61 + px] = v;
        }
    }
}

// ================= fc1: split-K partials =================
#define FC1_K      55815
#define FC1_CHUNK  768
#define FC1_NC     73
#define FC1_RT     15

// grid (15, 73), block 256. Wave w owns rows rt*8 + {2w, 2w+1}.
__global__ __launch_bounds__(256) void fc1_partial_k(
    const float* __restrict__ act /*(10, ACT_STRIDE)*/,
    const float* __restrict__ w   /*(120, 55815)*/,
    float* __restrict__ partials  /*(73,120,10)*/) {
    int rt  = blockIdx.x;
    int c   = blockIdx.y;
    int tid = threadIdx.x;
    int wave = tid >> 6, lane = tid & 63;
    int k0 = c * FC1_CHUNK;
    int k1 = k0 + FC1_CHUNK; if (k1 > FC1_K) k1 = FC1_K;
    int r0 = rt * 8 + wave * 2;
    const float* w0 = w + (size_t)r0 * FC1_K;
    const float* w1 = w + (size_t)(r0 + 1) * FC1_K;

    float acc0[10], acc1[10];
    #pragma unroll
    for (int b = 0; b < 10; ++b) { acc0[b] = 0.f; acc1[b] = 0.f; }

    for (int k = k0 + lane * 4; k < k1; k += 256) {
        if (k + 4 <= k1) {
            float4 a4[10];
            #pragma unroll
            for (int b = 0; b < 10; ++b)
                a4[b] = *reinterpret_cast<const float4*>(act + (size_t)b * ACT_STRIDE + k);
            float w00 = w0[k], w01 = w0[k + 1], w02 = w0[k + 2], w03 = w0[k + 3];
            float w10 = w1[k], w11 = w1[k + 1], w12 = w1[k + 2], w13 = w1[k + 3];
            #pragma unroll
            for (int b = 0; b < 10; ++b) {
                acc0[b] += w00 * a4[b].x + w01 * a4[b].y + w02 * a4[b].z + w03 * a4[b].w;
                acc1[b] += w10 * a4[b].x + w11 * a4[b].y + w12 * a4[b].z + w13 * a4[b].w;
            }
        } else {
            for (int j = 0; j < k1 - k; ++j) {
                float wv0 = w0[k + j], wv1 = w1[k + j];
                #pragma unroll
                for (int b = 0; b < 10; ++b) {
                    float av = act[(size_t)b * ACT_STRIDE + k + j];
                    acc0[b] += wv0 * av;
                    acc1[b] += wv1 * av;
                }
            }
        }
    }
    #pragma unroll
    for (int b = 0; b < 10; ++b) {
        float v0 = acc0[b], v1 = acc1[b];
        for (int off = 32; off > 0; off >>= 1) {
            v0 += __shfl_down(v0, off);
            v1 += __shfl_down(v1, off);
        }
        if (lane == 0) {
            size_t base = ((size_t)c * 120 + r0) * 10;
            partials[base + b]      = v0;
            partials[base + 10 + b] = v1;
        }
    }
}

// ===== fcA: fc1-reduce + fc2 + fc3. grid 10 (one block per batch) x 128 =====
__global__ __launch_bounds__(128) void fcA_k(
    const float* __restrict__ part /*(73,120,10)*/, const float* __restrict__ fc1_b,
    const float* __restrict__ fc2_w, const float* __restrict__ fc2_b,
    const float* __restrict__ fc3_w, const float* __restrict__ fc3_b,
    float* __restrict__ h3 /*(10,)*/) {
    const int b = blockIdx.x;
    const int tid = threadIdx.x;
    __shared__ float s_act[120];
    __shared__ float s_fc2[84];

    if (tid < 120) {
        float s = 0.f;
        for (int c = 0; c < FC1_NC; ++c) s += part[((size_t)c * 120 + tid) * 10 + b];
        s_act[tid] = fmaxf(s + fc1_b[tid], 0.f);
    }
    __syncthreads();
    if (tid < 84) {
        float acc = fc2_b[tid];
        #pragma unroll 4
        for (int k = 0; k < 120; ++k) acc += s_act[k] * fc2_w[tid * 120 + k];
        s_fc2[tid] = fmaxf(acc, 0.f);
    }
    __syncthreads();
    if (tid < 64) {
        float v = s_fc2[tid] * fc3_w[tid];
        if (tid < 20) v += s_fc2[tid + 64] * fc3_w[tid + 64];
        for (int off = 32; off > 0; off >>= 1) v += __shfl_down(v, off);
        if (tid == 0) h3[b] = v + fc3_b[0];
    }
}

// ===== clsB: qnn (redundant per block) + RBF partials. 64 blocks x 128 =====
__global__ __launch_bounds__(128) void clsB_k(
    const float* __restrict__ h3 /*(10,)*/,
    const float* __restrict__ qw1, const float* __restrict__ qw2,
    const float* __restrict__ ts /*(8192,5)*/, const float* __restrict__ kw /*(2,8192)*/,
    float* __restrict__ partials /*(64,2)*/) {
    int tid = threadIdx.x;
    __shared__ float s_h3[10], s_s1[20], s_fs[5];
    if (tid < 10) s_h3[tid] = h3[tid];
    __syncthreads();
    if (tid < 20) {
        float acc = 0.f;
        for (int b = 0; b < 10; ++b) acc += qw1[tid * 10 + b] * s_h3[b];
        s_s1[tid] = tanhf(acc);
    }
    __syncthreads();
    if (tid < 5) {
        float acc = 0.f;
        for (int j = 0; j < 20; ++j) acc += qw2[tid * 20 + j] * s_s1[j];
        s_fs[tid] = tanhf(acc);
    }
    __syncthreads();

    float f0 = s_fs[0], f1 = s_fs[1], f2 = s_fs[2], f3 = s_fs[3], f4 = s_fs[4];
    int n = blockIdx.x * 128 + tid;
    const float* t = ts + (size_t)n * 5;
    float d0 = f0 - t[0], d1 = f1 - t[1], d2 = f2 - t[2], d3 = f3 - t[3], d4 = f4 - t[4];
    float Kv = expf(-(d0 * d0 + d1 * d1 + d2 * d2 + d3 * d3 + d4 * d4));
    float a0 = Kv * kw[n];
    float a1 = Kv * kw[8192 + n];
    for (int off = 32; off > 0; off >>= 1) {
        a0 += __shfl_down(a0, off);
        a1 += __shfl_down(a1, off);
    }
    __shared__ float l0[2], l1[2];
    int wave = tid >> 6, lane = tid & 63;
    if (lane == 0) { l0[wave] = a0; l1[wave] = a1; }
    __syncthreads();
    if (tid == 0) {
        partials[blockIdx.x * 2 + 0] = l0[0] + l0[1];
        partials[blockIdx.x * 2 + 1] = l1[0] + l1[1];
    }
}

__global__ void clsC_k(const float* __restrict__ partials,
                       const float* __restrict__ kb, float* __restrict__ out) {
    int c = threadIdx.x;
    if (c < 2) {
        float acc = kb[c];
        for (int i = 0; i < 64; ++i) acc += partials[i * 2 + c];
        out[c] = acc;
    }
}

extern "C" void kernel_launch(void* const* d_in, const int* in_sizes, int n_in,
                              void* d_out, int out_size, void* d_ws, size_t ws_size,
                              hipStream_t stream) {
    const float* x        = (const float*)d_in[0];
    const float* conv1_w  = (const float*)d_in[1];
    const float* conv1_b  = (const float*)d_in[2];
    const float* conv2_w  = (const float*)d_in[3];
    const float* conv2_b  = (const float*)d_in[4];
    const float* fc1_w    = (const float*)d_in[5];
    const float* fc1_b    = (const float*)d_in[6];
    const float* fc2_w    = (const float*)d_in[7];
    const float* fc2_b    = (const float*)d_in[8];
    const float* fc3_w    = (const float*)d_in[9];
    const float* fc3_b    = (const float*)d_in[10];
    const float* qnn_w1   = (const float*)d_in[11];
    const float* qnn_w2   = (const float*)d_in[12];
    const float* tstates  = (const float*)d_in[13];
    const float* kcls_w   = (const float*)d_in[14];
    const float* kcls_b   = (const float*)d_in[15];

    float* ws = (float*)d_ws;
    float* p1       = ws;                  // 10*6*123*123 = 907740
    float* p2       = p1 + 907740;         // 10*ACT_STRIDE = 558160 (16B-aligned)
    float* fc1_part = p2 + 558160;         // 73*120*10 = 87600
    float* h3       = fc1_part + 87600;    // 16
    float* partials = h3 + 16;             // 128

    convpool1_k<<<dim3(10, 31, 4), 256, 0, stream>>>(x, conv1_w, conv1_b, p1);
    convpool2_k<<<dim3(10, 31, 4), 128, 0, stream>>>(p1, conv2_w, conv2_b, p2);
    fc1_partial_k<<<dim3(FC1_RT, FC1_NC), 256, 0, stream>>>(p2, fc1_w, fc1_part);
    fcA_k<<<10, 128, 0, stream>>>(fc1_part, fc1_b, fc2_w, fc2_b, fc3_w, fc3_b, h3);
    clsB_k<<<64, 128, 0, stream>>>(h3, qnn_w1, qnn_w2, tstates, kcls_w, partials);
    clsC_k<<<1, 64, 0, stream>>>(partials, kcls_b, (float*)d_out);
}